// Round 1
// baseline (1244.607 us; speedup 1.0000x reference)
//
#include <hip/hip_runtime.h>
#include <math.h>

#define NTOKEN 1024
#define NTOK2  2048
#define FD     64
#define BATCH  8

constexpr float DXC   = 2.0f/31.0f;
constexpr float DXDY  = DXC*DXC;
constexpr float SCALE = 0.125f;      // 1/sqrt(64)
constexpr float EPSC  = 1e-5f;
constexpr float SLOPEC= 0.01f;

// ---- workspace offsets (in floats) ----
#define OFF_VIN    0u         // 8*2048*64      = 1048576
#define OFF_W      1048576u   // 1024*1024
#define OFF_WF     2097152u   // 1024*1024
#define OFF_AIK    3145728u   // 1024*32
#define OFF_BJK    3178496u
#define OFF_AIF    3211264u
#define OFF_BJF    3244032u
#define OFF_GPART  3276800u   // 8*32*4096 = 1048576
#define OFF_GSPART 4325376u   // 8*32*64   = 16384
#define OFF_G      4341760u   // 8*4096
#define OFF_GS     4374528u   // 8*64
#define OFF_S      4375040u   // 8*4*4096 = 131072
#define OFF_T      4506112u   // 8*4096
#define OFF_TV     4538880u   // 8*64
#define OFF_T3     4539392u   // 8*4096
#define OFF_T3V    4572160u   // 8*64
#define OFF_WSP    4572672u   // 8*1024
#define OFF_WFSP   4580864u   // 8*1024
#define OFF_PPART  4589056u   // 8*4*1024*64 = 2097152
// total 6686208 floats ~= 25.5 MiB

__device__ __forceinline__ float lrelu(float x){ return fmaxf(x, SLOPEC*x); }

__device__ __forceinline__ float wsum64(float v){
  #pragma unroll
  for(int off=32; off; off>>=1) v += __shfl_xor(v, off);
  return v;
}

// ---------------- edge first-layer tables: Ai (from gi) and Bj (from gj, +bias) ----
__global__ void k_edge_tables(const float* __restrict__ kW0, const float* __restrict__ kb0,
                              const float* __restrict__ fW0, const float* __restrict__ fb0,
                              float* __restrict__ ws)
{
  int i = blockIdx.x, c = threadIdx.x;           // grid 1024, block 32
  float x = -1.f + DXC*(float)(i>>5);
  float y = -1.f + DXC*(float)(i&31);
  ws[OFF_AIK + i*32 + c] = kW0[c*4+0]*x + kW0[c*4+1]*y;
  ws[OFF_BJK + i*32 + c] = kW0[c*4+2]*x + kW0[c*4+3]*y + kb0[c];
  ws[OFF_AIF + i*32 + c] = fW0[c*4+0]*x + fW0[c*4+1]*y;
  ws[OFF_BJF + i*32 + c] = fW0[c*4+2]*x + fW0[c*4+3]*y + fb0[c];
}

// ---------------- edge MLPs: weight[i][j], weightf[i][j] -----------------------------
__global__ __launch_bounds__(256) void k_edge_mlp(
    const float* __restrict__ kW1, const float* __restrict__ kb1,
    const float* __restrict__ kW2, const float* __restrict__ kb2,
    const float* __restrict__ fW1, const float* __restrict__ fb1,
    const float* __restrict__ fW2, const float* __restrict__ fb2,
    const float* __restrict__ ws, float* __restrict__ weight, float* __restrict__ weightf)
{
  int tid = threadIdx.x;
  int i = blockIdx.x >> 2;                       // uniform per block
  int j = ((blockIdx.x & 3) << 8) | tid;
  const float* aik = ws + OFF_AIK + i*32;
  const float* aif = ws + OFF_AIF + i*32;
  const float4* bjk4 = (const float4*)(ws + OFF_BJK + j*32);
  const float4* bjf4 = (const float4*)(ws + OFF_BJF + j*32);
  float h0k[32], h0f[32];
  #pragma unroll
  for(int c4=0;c4<8;c4++){
    float4 vk = bjk4[c4], vf = bjf4[c4];
    h0k[c4*4+0]=lrelu(aik[c4*4+0]+vk.x); h0k[c4*4+1]=lrelu(aik[c4*4+1]+vk.y);
    h0k[c4*4+2]=lrelu(aik[c4*4+2]+vk.z); h0k[c4*4+3]=lrelu(aik[c4*4+3]+vk.w);
    h0f[c4*4+0]=lrelu(aif[c4*4+0]+vf.x); h0f[c4*4+1]=lrelu(aif[c4*4+1]+vf.y);
    h0f[c4*4+2]=lrelu(aif[c4*4+2]+vf.z); h0f[c4*4+3]=lrelu(aif[c4*4+3]+vf.w);
  }
  float ak = kb2[0], af = fb2[0];
  #pragma unroll 8
  for(int o=0;o<64;o++){
    float sk = kb1[o], sf = fb1[o];
    #pragma unroll
    for(int c=0;c<32;c++){ sk += kW1[o*32+c]*h0k[c]; sf += fW1[o*32+c]*h0f[c]; }
    ak += kW2[o]*lrelu(sk);
    af += fW2[o]*lrelu(sf);
  }
  weight [i*1024+j] = ak;
  weightf[i*1024+j] = af;
}

// ---------------- LN0 over (2048,64) per batch --------------------------------------
__global__ __launch_bounds__(1024) void k_ln0(const float* __restrict__ xy,
                                              const float* __restrict__ g,
                                              const float* __restrict__ bb,
                                              float* __restrict__ Vin)
{
  const int N = NTOK2*FD;
  int b = blockIdx.x, tid = threadIdx.x;
  const float* xb = xy + (size_t)b*N;
  float s=0.f, ss=0.f;
  for(int idx=tid; idx<N; idx+=1024){ float v=xb[idx]; s+=v; ss+=v*v; }
  __shared__ float red[1024];
  red[tid]=s; __syncthreads();
  for(int off=512; off>0; off>>=1){ if(tid<off) red[tid]+=red[tid+off]; __syncthreads(); }
  float mean = red[0]*(1.0f/N);
  __syncthreads();
  red[tid]=ss; __syncthreads();
  for(int off=512; off>0; off>>=1){ if(tid<off) red[tid]+=red[tid+off]; __syncthreads(); }
  float var = red[0]*(1.0f/N) - mean*mean;
  float inv = 1.0f/sqrtf(var + EPSC);
  float* vb = Vin + (size_t)b*N;
  for(int idx=tid; idx<N; idx+=1024) vb[idx] = (xb[idx]-mean)*inv*g[idx] + bb[idx];
}

// ---------------- partial Gram: G[c,f] = sum_m Xc[m,c]*Xf[m,f] (64-row chunks) -------
__global__ __launch_bounds__(64) void k_gram_part(const float* __restrict__ Xc,
                                                  const float* __restrict__ Xf,
                                                  int nchunks,
                                                  float* __restrict__ Gpart,
                                                  float* __restrict__ gspart)
{
  int bid = blockIdx.x;
  int b = bid / nchunks, ch = bid % nchunks;
  int lane = threadIdx.x;
  const float* xc = Xc + ((size_t)b*NTOK2 + ch*64)*FD;
  const float* xf = Xf + ((size_t)b*NTOK2 + ch*64)*FD;
  float acc[64];
  #pragma unroll
  for(int c=0;c<64;c++) acc[c]=0.f;
  float cs=0.f;
  for(int m=0;m<64;m++){
    const float* rc = xc + m*FD;    // uniform row -> scalar loads
    float vf = xf[m*FD + lane];
    cs += vf;
    #pragma unroll
    for(int c=0;c<64;c++) acc[c] += rc[c]*vf;
  }
  float* gp = Gpart + (size_t)bid*4096;
  #pragma unroll
  for(int c=0;c<64;c++) gp[c*64+lane]=acc[c];
  gspart[bid*64+lane]=cs;
}

__global__ __launch_bounds__(256) void k_gram_reduce(const float* __restrict__ Gpart,
                                                     const float* __restrict__ gspart,
                                                     int nchunks,
                                                     float* __restrict__ G,
                                                     float* __restrict__ gs)
{
  int b = blockIdx.x, tid = threadIdx.x;
  for(int e=tid;e<4096;e+=256){
    float s=0.f;
    for(int c=0;c<nchunks;c++) s += Gpart[((size_t)(b*nchunks+c))*4096+e];
    G[b*4096+e]=s;
  }
  if(tid<64){
    float s=0.f;
    for(int c=0;c<nchunks;c++) s += gspart[(b*nchunks+c)*64+tid];
    gs[b*64+tid]=s;
  }
}

// ---------------- S[b,h] = Wk[j,h] @ G[b] + bk ⊗ gs ---------------------------------
__global__ __launch_bounds__(256) void k_S(const float* __restrict__ Wk,
                                           const float* __restrict__ bk, int j,
                                           const float* __restrict__ G,
                                           const float* __restrict__ gs,
                                           float* __restrict__ S)
{
  int b = blockIdx.x>>2, h = blockIdx.x&3;
  int tid = threadIdx.x;
  __shared__ float sG[4096];
  for(int e=tid;e<4096;e+=256) sG[e]=G[b*4096+e];
  __syncthreads();
  int lane = tid&63;
  int wid = __builtin_amdgcn_readfirstlane(tid>>6);
  const float* wk = Wk + (size_t)((j*4+h)*64)*64;
  float gsl = gs[b*64+lane];
  float acc[16];
  #pragma unroll
  for(int r=0;r<16;r++) acc[r] = bk[(j*4+h)*64 + (wid+4*r)] * gsl;
  for(int c=0;c<64;c++){
    float gv = sG[c*64+lane];
    #pragma unroll
    for(int r=0;r<16;r++) acc[r] += wk[(wid+4*r)*64+c]*gv;
  }
  float* sp = S + (size_t)(b*4+h)*4096;
  #pragma unroll
  for(int r=0;r<16;r++) sp[(wid+4*r)*64+lane] = acc[r];
}

// ---------------- T[b] = sum_h Wq[j,h]^T S[b,h];  t[b] = sum_h bq^T S ----------------
__global__ __launch_bounds__(256) void k_makeT(const float* __restrict__ Wq,
                                               const float* __restrict__ bq, int j,
                                               const float* __restrict__ S,
                                               float* __restrict__ T,
                                               float* __restrict__ tv)
{
  int b = blockIdx.x, tid = threadIdx.x;
  int lane = tid&63;
  int wid = __builtin_amdgcn_readfirstlane(tid>>6);
  __shared__ float sS[4096];
  float acc[16];
  #pragma unroll
  for(int r=0;r<16;r++) acc[r]=0.f;
  float tacc=0.f;
  for(int h=0;h<4;h++){
    __syncthreads();
    for(int e=tid;e<4096;e+=256) sS[e]=S[(size_t)b*16384 + h*4096 + e];
    __syncthreads();
    const float* wq  = Wq + (size_t)(j*4+h)*4096;
    const float* bqh = bq + (j*4+h)*64;
    for(int k=0;k<64;k++){
      float sv = sS[k*64+lane];
      #pragma unroll
      for(int r=0;r<16;r++) acc[r] += wq[k*64 + (wid+4*r)]*sv;
      tacc += bqh[k]*sv;
    }
  }
  #pragma unroll
  for(int r=0;r<16;r++) T[b*4096 + (wid+4*r)*64 + lane] = acc[r];
  if(wid==0) tv[b*64+lane] = tacc;
}

// ---------------- mid = dxdy*scale*(Vin@T + 1⊗t); Vin = LN_row(mid)+Vin -------------
__global__ __launch_bounds__(256) void k_mid_ln(float* __restrict__ Vin,
                                                const float* __restrict__ T,
                                                const float* __restrict__ tv,
                                                const float* __restrict__ lng,
                                                const float* __restrict__ lnb, int j)
{
  int wid = __builtin_amdgcn_readfirstlane(threadIdx.x>>6);
  int row = blockIdx.x*4 + wid;              // b*2048+n, total 16384
  int lane = threadIdx.x&63;
  int b = row>>11;
  const float* Tb = T + b*4096;
  float* vrow = Vin + (size_t)row*64;
  float vl = vrow[lane];
  float m = tv[b*64+lane];
  #pragma unroll
  for(int c=0;c<64;c++) m += __shfl(vl, c) * Tb[c*64+lane];
  m *= DXDY*SCALE;
  float mean = wsum64(m)*(1.0f/64.0f);
  float d = m - mean;
  float var = wsum64(d*d)*(1.0f/64.0f);
  float y = d*(1.0f/sqrtf(var+EPSC))*lng[j*64+lane] + lnb[j*64+lane];
  vrow[lane] = y + vl;
}

// ---------------- partial column sums of weight/weightf ------------------------------
__global__ __launch_bounds__(256) void k_wsum_part(const float* __restrict__ weight,
                                                   const float* __restrict__ weightf,
                                                   float* __restrict__ wsp,
                                                   float* __restrict__ wfsp)
{
  int jjblk = blockIdx.x&3, ns = blockIdx.x>>2;   // grid 32
  int jj = jjblk*256 + threadIdx.x;
  float s=0.f, sf=0.f;
  for(int n=ns*128; n<ns*128+128; n++){ s += weight[n*1024+jj]; sf += weightf[n*1024+jj]; }
  wsp [ns*1024+jj]=s;
  wfsp[ns*1024+jj]=sf;
}

// ---------------- Ppart = partial of weight^T@Vinu + weightf^T@Vinf ------------------
__global__ __launch_bounds__(256) void k_pw(const float* __restrict__ weight,
                                            const float* __restrict__ weightf,
                                            const float* __restrict__ Vin,
                                            float* __restrict__ Ppart)
{
  int bid = blockIdx.x;                           // 8b x 16jjt x 4ns = 512
  int ns = bid&3, jjt = (bid>>2)&15, b = bid>>6;
  int lane = threadIdx.x&63;
  int wid = __builtin_amdgcn_readfirstlane(threadIdx.x>>6);
  int jj0 = jjt*64 + wid*16;
  const float* Vu = Vin + (size_t)b*NTOK2*FD;
  const float* Vf = Vu + NTOKEN*FD;
  float acc[16];
  #pragma unroll
  for(int q=0;q<16;q++) acc[q]=0.f;
  for(int n=ns*256; n<ns*256+256; n++){
    float vu = Vu[n*64+lane];
    float vf = Vf[n*64+lane];
    const float* wr  = weight  + n*1024 + jj0;    // wave-uniform -> scalar loads
    const float* wfr = weightf + n*1024 + jj0;
    #pragma unroll
    for(int q=0;q<16;q++) acc[q] += wr[q]*vu + wfr[q]*vf;
  }
  float* pp = Ppart + ((size_t)(b*4+ns)*1024 + jjt*64 + wid*16)*64;
  #pragma unroll
  for(int q=0;q<16;q++) pp[q*64+lane]=acc[q];
}

// ---------------- result = dxdy^2*scale*(P@T3 + (wsum+wfsum)⊗t3) --------------------
__global__ __launch_bounds__(256) void k_final(const float* __restrict__ Ppart,
                                               const float* __restrict__ T3,
                                               const float* __restrict__ t3,
                                               const float* __restrict__ wsp,
                                               const float* __restrict__ wfsp,
                                               float* __restrict__ out)
{
  int wid = __builtin_amdgcn_readfirstlane(threadIdx.x>>6);
  int row = blockIdx.x*4 + wid;                   // b*1024+jj, total 8192
  int lane = threadIdx.x&63;
  int b = row>>10, jj = row&1023;
  float p = 0.f;
  #pragma unroll
  for(int ns=0; ns<4; ns++) p += Ppart[((size_t)(b*4+ns)*1024 + jj)*64 + lane];
  float wsm = 0.f;
  #pragma unroll
  for(int ns=0; ns<8; ns++) wsm += wsp[ns*1024+jj] + wfsp[ns*1024+jj];
  const float* Tb = T3 + b*4096;
  float acc = wsm * t3[b*64+lane];
  #pragma unroll
  for(int c=0;c<64;c++) acc += __shfl(p, c) * Tb[c*64+lane];
  out[(size_t)row*64+lane] = acc * (DXDY*DXDY*SCALE);
}

extern "C" void kernel_launch(void* const* d_in, const int* in_sizes, int n_in,
                              void* d_out, int out_size, void* d_ws, size_t ws_size,
                              hipStream_t stream)
{
  (void)in_sizes; (void)n_in; (void)out_size; (void)ws_size;
  const float* xy   = (const float*)d_in[0];
  const float* kW0  = (const float*)d_in[1];
  const float* kb0  = (const float*)d_in[2];
  const float* kW1  = (const float*)d_in[3];
  const float* kb1  = (const float*)d_in[4];
  const float* kW2  = (const float*)d_in[5];
  const float* kb2  = (const float*)d_in[6];
  const float* fW0  = (const float*)d_in[7];
  const float* fb0  = (const float*)d_in[8];
  const float* fW1  = (const float*)d_in[9];
  const float* fb1  = (const float*)d_in[10];
  const float* fW2  = (const float*)d_in[11];
  const float* fb2  = (const float*)d_in[12];
  const float* Wq   = (const float*)d_in[13];
  const float* bq   = (const float*)d_in[14];
  const float* Wk   = (const float*)d_in[15];
  const float* bk   = (const float*)d_in[16];
  const float* ln0g = (const float*)d_in[17];
  const float* ln0b = (const float*)d_in[18];
  const float* lng  = (const float*)d_in[19];
  const float* lnb  = (const float*)d_in[20];
  float* out = (float*)d_out;
  float* ws  = (float*)d_ws;

  float* Vin    = ws + OFF_VIN;
  float* weight = ws + OFF_W;
  float* weightf= ws + OFF_WF;
  float* Gpart  = ws + OFF_GPART;
  float* gspart = ws + OFF_GSPART;
  float* G      = ws + OFF_G;
  float* gs     = ws + OFF_GS;
  float* S      = ws + OFF_S;
  float* T      = ws + OFF_T;
  float* tvv    = ws + OFF_TV;
  float* T3     = ws + OFF_T3;
  float* t3     = ws + OFF_T3V;
  float* wsp    = ws + OFF_WSP;
  float* wfsp   = ws + OFF_WFSP;
  float* Ppart  = ws + OFF_PPART;

  k_edge_tables<<<1024, 32, 0, stream>>>(kW0, kb0, fW0, fb0, ws);
  k_edge_mlp<<<4096, 256, 0, stream>>>(kW1, kb1, kW2, kb2, fW1, fb1, fW2, fb2,
                                       ws, weight, weightf);
  k_ln0<<<BATCH, 1024, 0, stream>>>(xy, ln0g, ln0b, Vin);

  for(int j=0;j<3;j++){
    k_gram_part<<<BATCH*32, 64, 0, stream>>>(Vin, Vin, 32, Gpart, gspart);
    k_gram_reduce<<<BATCH, 256, 0, stream>>>(Gpart, gspart, 32, G, gs);
    k_S<<<BATCH*4, 256, 0, stream>>>(Wk, bk, j, G, gs, S);
    k_makeT<<<BATCH, 256, 0, stream>>>(Wq, bq, j, S, T, tvv);
    k_mid_ln<<<BATCH*2048/4, 256, 0, stream>>>(Vin, T, tvv, lng, lnb, j);
  }

  // final layer: Gu = Vinu^T @ xu, su = colsum(xu)
  k_gram_part<<<BATCH*16, 64, 0, stream>>>(Vin, xy, 16, Gpart, gspart);
  k_gram_reduce<<<BATCH, 256, 0, stream>>>(Gpart, gspart, 16, G, gs);
  k_S<<<BATCH*4, 256, 0, stream>>>(Wk, bk, 3, G, gs, S);
  k_makeT<<<BATCH, 256, 0, stream>>>(Wq, bq, 3, S, T3, t3);

  k_wsum_part<<<32, 256, 0, stream>>>(weight, weightf, wsp, wfsp);
  k_pw<<<512, 256, 0, stream>>>(weight, weightf, Vin, Ppart);
  k_final<<<BATCH*1024/4, 256, 0, stream>>>(Ppart, T3, t3, wsp, wfsp, out);
}

// Round 2
// 800.951 us; speedup vs baseline: 1.5539x; 1.5539x over previous
//
#include <hip/hip_runtime.h>
#include <math.h>

#define NTOKEN 1024
#define NTOK2  2048
#define FD     64
#define BATCH  8

constexpr float DXC   = 2.0f/31.0f;
constexpr float DXDY  = DXC*DXC;
constexpr float SCALE = 0.125f;      // 1/sqrt(64), folded into M/u/v/c by k_prep
constexpr float EPSC  = 1e-5f;
constexpr float SLOPEC= 0.01f;

// ---- workspace offsets (floats) ----
#define OFF_VIN    0u         // 1048576
#define OFF_W      1048576u   // 1048576
#define OFF_WF     2097152u   // 1048576
#define OFF_AIK    3145728u   // 32768
#define OFF_BJK    3178496u   // 32768
#define OFF_AIF    3211264u   // 32768
#define OFF_BJF    3244032u   // 32768
#define OFF_GPART  3276800u   // 8*32*4096 = 1048576
#define OFF_GSPART 4325376u   // 8*32*64   = 16384
#define OFF_M      4341760u   // 4*4096
#define OFF_U      4358144u   // 256
#define OFF_V      4358400u   // 256
#define OFF_C      4358656u   // 64 (pad)
#define OFF_LNP    4358720u   // 256
#define OFF_T      4358976u   // 32768
#define OFF_TV     4391744u   // 512
#define OFF_T3     4392256u   // 32768
#define OFF_T3V    4425024u   // 512
#define OFF_WSP    4425536u   // 8192
#define OFF_WFSP   4433728u   // 8192
#define OFF_PPART  4441920u   // 2097152
// total 6539072 floats = 26.2 MB (<= round-1's 26.7 MB which fit)

__device__ __forceinline__ float lrelu(float x){ return fmaxf(x, SLOPEC*x); }

__device__ __forceinline__ float wsum64(float v){
  #pragma unroll
  for(int off=32; off; off>>=1) v += __shfl_xor(v, off);
  return v;
}

// ---------------- edge first-layer tables ----------------
__global__ void k_tables(const float* __restrict__ kW0, const float* __restrict__ kb0,
                         const float* __restrict__ fW0, const float* __restrict__ fb0,
                         float* __restrict__ ws)
{
  int i = blockIdx.x, c = threadIdx.x;           // grid 1024, block 32
  float x = -1.f + DXC*(float)(i>>5);
  float y = -1.f + DXC*(float)(i&31);
  ws[OFF_AIK + i*32 + c] = kW0[c*4+0]*x + kW0[c*4+1]*y;
  ws[OFF_BJK + i*32 + c] = kW0[c*4+2]*x + kW0[c*4+3]*y + kb0[c];
  ws[OFF_AIF + i*32 + c] = fW0[c*4+0]*x + fW0[c*4+1]*y;
  ws[OFF_BJF + i*32 + c] = fW0[c*4+2]*x + fW0[c*4+3]*y + fb0[c];
}

// ---------------- edge MLP: one MLP per thread (no register spill) ----------------
__global__ __launch_bounds__(256) void k_mlp(
    const float* __restrict__ kW1, const float* __restrict__ kb1,
    const float* __restrict__ kW2, const float* __restrict__ kb2,
    const float* __restrict__ fW1, const float* __restrict__ fb1,
    const float* __restrict__ fW2, const float* __restrict__ fb2,
    const float* __restrict__ ws, float* __restrict__ w_out, float* __restrict__ wf_out)
{
  int tid = threadIdx.x;
  int blk = blockIdx.x;                          // grid 8192
  int i = blk >> 3;
  int sub = blk & 7;
  int which = sub >> 2;                          // 0 = k-MLP, 1 = f-MLP
  int j = ((sub & 3) << 8) | tid;
  const float* W1 = which ? fW1 : kW1;
  const float* b1 = which ? fb1 : kb1;
  const float* W2 = which ? fW2 : kW2;
  const float* b2 = which ? fb2 : kb2;
  const float*  Ai = ws + (which ? OFF_AIF : OFF_AIK) + i*32;
  const float4* Bj = (const float4*)(ws + (which ? OFF_BJF : OFF_BJK) + j*32);
  float* outp = which ? wf_out : w_out;
  float h0[32];
  #pragma unroll
  for(int c4=0;c4<8;c4++){
    float4 v = Bj[c4];
    h0[c4*4+0]=lrelu(Ai[c4*4+0]+v.x);
    h0[c4*4+1]=lrelu(Ai[c4*4+1]+v.y);
    h0[c4*4+2]=lrelu(Ai[c4*4+2]+v.z);
    h0[c4*4+3]=lrelu(Ai[c4*4+3]+v.w);
  }
  float a = b2[0];
  #pragma unroll 4
  for(int o=0;o<64;o++){
    float sacc = b1[o];
    #pragma unroll
    for(int c=0;c<32;c++) sacc += W1[o*32+c]*h0[c];
    a += W2[o]*lrelu(sacc);
  }
  outp[i*1024+j] = a;
}

// ---------------- LN0 partial sums ----------------
__global__ __launch_bounds__(256) void k_ln0_part(const float* __restrict__ xy,
                                                  float* __restrict__ lnp)
{
  int b = blockIdx.x>>4, blk = blockIdx.x&15;    // grid 128
  int tid = threadIdx.x;
  const float4* x4 = (const float4*)(xy + (size_t)b*131072 + blk*8192);
  float s=0.f, ss=0.f;
  #pragma unroll
  for(int k2=0;k2<8;k2++){
    float4 v = x4[tid + k2*256];
    s  += v.x+v.y+v.z+v.w;
    ss += v.x*v.x+v.y*v.y+v.z*v.z+v.w*v.w;
  }
  s = wsum64(s); ss = wsum64(ss);
  __shared__ float r1[4], r2[4];
  int wid = tid>>6;
  if((tid&63)==0){ r1[wid]=s; r2[wid]=ss; }
  __syncthreads();
  if(tid==0){
    lnp[(b*16+blk)*2  ] = r1[0]+r1[1]+r1[2]+r1[3];
    lnp[(b*16+blk)*2+1] = r2[0]+r2[1]+r2[2]+r2[3];
  }
}

// ---------------- weight-only precompute: M_j, u_j, v_j, c_j (scale folded) --------
__global__ __launch_bounds__(256) void k_prep(const float* __restrict__ Wq,
                                              const float* __restrict__ bq,
                                              const float* __restrict__ Wk,
                                              const float* __restrict__ bk,
                                              float* __restrict__ M, float* __restrict__ u,
                                              float* __restrict__ v, float* __restrict__ cc)
{
  int j = blockIdx.x;                            // grid 4
  int tid = threadIdx.x, lane = tid&63;
  int wid = __builtin_amdgcn_readfirstlane(tid>>6);
  float mac[16], uac[16];
  #pragma unroll
  for(int r=0;r<16;r++){ mac[r]=0.f; uac[r]=0.f; }
  float vac=0.f, cac=0.f;
  for(int hk=0; hk<256; hk++){
    const float* wqrow = Wq + ((size_t)j*256 + hk)*64;
    const float* wkrow = Wk + ((size_t)j*256 + hk)*64;
    float wkl = wkrow[lane];
    float bkk = bk[j*256+hk];
    float bqk = bq[j*256+hk];
    #pragma unroll
    for(int r=0;r<16;r++){
      float wq = wqrow[wid*16+r];                // wave-uniform -> scalar load
      mac[r] += wq*wkl;
      uac[r] += wq*bkk;
    }
    vac += bqk*wkl;
    cac += bqk*bkk;
  }
  #pragma unroll
  for(int r=0;r<16;r++) M[j*4096 + (wid*16+r)*64 + lane] = mac[r]*SCALE;
  if(lane==0){
    #pragma unroll
    for(int r=0;r<16;r++) u[j*64 + wid*16+r] = uac[r]*SCALE;
  }
  if(wid==0) v[j*64+lane] = vac*SCALE;
  if(tid==0) cc[j] = cac*SCALE;
}

// ---------------- LN0 apply + Gram partial (64-row tiles) ----------------
__global__ __launch_bounds__(256) void k_ln0ag(const float* __restrict__ xy,
    const float* __restrict__ g, const float* __restrict__ bb,
    const float* __restrict__ lnp,
    float* __restrict__ Vin, float* __restrict__ Gpart, float* __restrict__ gspart)
{
  __shared__ float sV[64][64];
  int b = blockIdx.x>>5, ch = blockIdx.x&31;     // grid 256
  int tid = threadIdx.x, lane = tid&63;
  int wid = __builtin_amdgcn_readfirstlane(tid>>6);
  float s=0.f, ss=0.f;
  #pragma unroll
  for(int k2=0;k2<16;k2++){ s += lnp[(b*16+k2)*2]; ss += lnp[(b*16+k2)*2+1]; }
  float mean = s*(1.0f/131072.0f);
  float var  = ss*(1.0f/131072.0f) - mean*mean;
  float inv  = 1.0f/sqrtf(var+EPSC);
  const float4* x4 = (const float4*)(xy + ((size_t)b*2048 + ch*64)*64);
  const float4* g4 = (const float4*)(g  + (size_t)ch*4096);
  const float4* b4 = (const float4*)(bb + (size_t)ch*4096);
  float4* vo4 = (float4*)(Vin + ((size_t)b*2048 + ch*64)*64);
  float4* sv4 = (float4*)&sV[0][0];
  for(int e=tid;e<1024;e+=256){
    float4 xv=x4[e], gv=g4[e], bv=b4[e];
    float4 r;
    r.x=(xv.x-mean)*inv*gv.x+bv.x;
    r.y=(xv.y-mean)*inv*gv.y+bv.y;
    r.z=(xv.z-mean)*inv*gv.z+bv.z;
    r.w=(xv.w-mean)*inv*gv.w+bv.w;
    vo4[e]=r; sv4[e]=r;
  }
  __syncthreads();
  float acc[16];
  #pragma unroll
  for(int q=0;q<16;q++) acc[q]=0.f;
  float gsa=0.f;
  for(int m=0;m<64;m++){
    const float4* cp = (const float4*)&sV[m][wid*16];
    float vml = sV[m][lane];
    float4 a0=cp[0],a1=cp[1],a2=cp[2],a3=cp[3];
    acc[0]+=a0.x*vml; acc[1]+=a0.y*vml; acc[2]+=a0.z*vml; acc[3]+=a0.w*vml;
    acc[4]+=a1.x*vml; acc[5]+=a1.y*vml; acc[6]+=a1.z*vml; acc[7]+=a1.w*vml;
    acc[8]+=a2.x*vml; acc[9]+=a2.y*vml; acc[10]+=a2.z*vml; acc[11]+=a2.w*vml;
    acc[12]+=a3.x*vml; acc[13]+=a3.y*vml; acc[14]+=a3.z*vml; acc[15]+=a3.w*vml;
    gsa += vml;
  }
  float* gp = Gpart + ((size_t)(b*32+ch))*4096 + wid*16*64;
  #pragma unroll
  for(int q=0;q<16;q++) gp[q*64+lane]=acc[q];
  if(wid==0) gspart[(b*32+ch)*64+lane]=gsa;
}

// ---------------- reduce Gram + T = M@G + u⊗gs, t = v^T G + c*gs ----------------
__global__ __launch_bounds__(256) void k_redT(const float* __restrict__ Gpart,
     const float* __restrict__ gspart, int nchunks,
     const float* __restrict__ M, const float* __restrict__ u,
     const float* __restrict__ v, const float* __restrict__ cc, int j,
     float* __restrict__ T, float* __restrict__ tv)
{
  __shared__ float sG[4096];
  __shared__ float sgs[64];
  int b = blockIdx.x, tid = threadIdx.x;         // grid 8
  for(int e=tid;e<4096;e+=256){
    float s=0.f;
    for(int c=0;c<nchunks;c++) s += Gpart[((size_t)(b*nchunks+c))*4096+e];
    sG[e]=s;
  }
  if(tid<64){
    float s=0.f;
    for(int c=0;c<nchunks;c++) s += gspart[(b*nchunks+c)*64+tid];
    sgs[tid]=s;
  }
  __syncthreads();
  int lane = tid&63;
  int wid = __builtin_amdgcn_readfirstlane(tid>>6);
  const float* Mj = M + j*4096;
  const float* uj = u + j*64;
  const float* vj = v + j*64;
  float gsl = sgs[lane];
  float acc[16];
  #pragma unroll
  for(int r=0;r<16;r++) acc[r] = uj[wid*16+r]*gsl;
  float tacc = cc[j]*gsl;
  for(int c=0;c<64;c++){
    float gv = sG[c*64+lane];
    #pragma unroll
    for(int r=0;r<16;r++) acc[r] += Mj[(wid*16+r)*64+c]*gv;
    tacc += vj[c]*gv;
  }
  #pragma unroll
  for(int r=0;r<16;r++) T[b*4096 + (wid*16+r)*64 + lane] = acc[r];
  if(wid==0) tv[b*64+lane] = tacc;
}

// ---------------- mid = dxdy*(Vin@T + 1⊗t); Vin = LN_row(mid)+Vin; [+ Gram] --------
__global__ __launch_bounds__(256) void k_mid_gram(
    float* __restrict__ Vin, const float* __restrict__ T, const float* __restrict__ tv,
    const float* __restrict__ lng, const float* __restrict__ lnb, int j, int do_gram,
    float* __restrict__ Gpart, float* __restrict__ gspart)
{
  __shared__ float sV[64][64];
  int b = blockIdx.x>>5, ch = blockIdx.x&31;     // grid 256
  int tid = threadIdx.x, lane = tid&63;
  int wid = __builtin_amdgcn_readfirstlane(tid>>6);
  const float* Tb = T + b*4096;
  float Tcol[64];
  #pragma unroll
  for(int c=0;c<64;c++) Tcol[c] = Tb[c*64+lane];
  float tvl = tv[b*64+lane];
  float gl = lng[j*64+lane], bl = lnb[j*64+lane];
  float* vbase = Vin + ((size_t)b*2048 + ch*64)*64;
  const float4* vb4 = (const float4*)vbase;
  float4* sv4 = (float4*)&sV[0][0];
  for(int e=tid;e<1024;e+=256) sv4[e]=vb4[e];
  __syncthreads();
  for(int rr=0;rr<16;rr++){
    int r = wid*16+rr;
    const float4* rp = (const float4*)&sV[r][0];
    float vl_old = sV[r][lane];
    float m = tvl;
    #pragma unroll
    for(int c4=0;c4<16;c4++){
      float4 vv = rp[c4];                        // ds_read_b128 broadcast
      m += vv.x*Tcol[c4*4] + vv.y*Tcol[c4*4+1] + vv.z*Tcol[c4*4+2] + vv.w*Tcol[c4*4+3];
    }
    m *= DXDY;
    float mean = wsum64(m)*(1.0f/64.0f);
    float d = m - mean;
    float var = wsum64(d*d)*(1.0f/64.0f);
    float y = d*(1.0f/sqrtf(var+EPSC))*gl + bl + vl_old;
    vbase[r*64+lane] = y;
    sV[r][lane] = y;                             // wave touches only its own rows
  }
  if(do_gram){
    __syncthreads();
    float acc[16];
    #pragma unroll
    for(int q=0;q<16;q++) acc[q]=0.f;
    float gsa=0.f;
    for(int m=0;m<64;m++){
      const float4* cp = (const float4*)&sV[m][wid*16];
      float vml = sV[m][lane];
      float4 a0=cp[0],a1=cp[1],a2=cp[2],a3=cp[3];
      acc[0]+=a0.x*vml; acc[1]+=a0.y*vml; acc[2]+=a0.z*vml; acc[3]+=a0.w*vml;
      acc[4]+=a1.x*vml; acc[5]+=a1.y*vml; acc[6]+=a1.z*vml; acc[7]+=a1.w*vml;
      acc[8]+=a2.x*vml; acc[9]+=a2.y*vml; acc[10]+=a2.z*vml; acc[11]+=a2.w*vml;
      acc[12]+=a3.x*vml; acc[13]+=a3.y*vml; acc[14]+=a3.z*vml; acc[15]+=a3.w*vml;
      gsa += vml;
    }
    float* gp = Gpart + ((size_t)(b*32+ch))*4096 + wid*16*64;
    #pragma unroll
    for(int q=0;q<16;q++) gp[q*64+lane]=acc[q];
    if(wid==0) gspart[(b*32+ch)*64+lane]=gsa;
  }
}

// ---------------- final cross-Gram: G = Vin_u^T @ xu, gs = colsum(xu) --------------
__global__ __launch_bounds__(256) void k_gram_fin(const float* __restrict__ Vin,
    const float* __restrict__ xy, float* __restrict__ Gpart, float* __restrict__ gspart)
{
  __shared__ float sA[64][64];
  __shared__ float sB[64][64];
  int b = blockIdx.x>>4, ch = blockIdx.x&15;     // grid 128, first 1024 rows only
  int tid = threadIdx.x, lane = tid&63;
  int wid = __builtin_amdgcn_readfirstlane(tid>>6);
  const float4* a4 = (const float4*)(Vin + ((size_t)b*2048 + ch*64)*64);
  const float4* b4 = (const float4*)(xy  + ((size_t)b*2048 + ch*64)*64);
  float4* sa4 = (float4*)&sA[0][0];
  float4* sb4 = (float4*)&sB[0][0];
  for(int e=tid;e<1024;e+=256){ sa4[e]=a4[e]; sb4[e]=b4[e]; }
  __syncthreads();
  float acc[16];
  #pragma unroll
  for(int q=0;q<16;q++) acc[q]=0.f;
  float gsa=0.f;
  for(int m=0;m<64;m++){
    const float4* cp = (const float4*)&sA[m][wid*16];
    float bml = sB[m][lane];
    float4 a0=cp[0],a1=cp[1],a2=cp[2],a3=cp[3];
    acc[0]+=a0.x*bml; acc[1]+=a0.y*bml; acc[2]+=a0.z*bml; acc[3]+=a0.w*bml;
    acc[4]+=a1.x*bml; acc[5]+=a1.y*bml; acc[6]+=a1.z*bml; acc[7]+=a1.w*bml;
    acc[8]+=a2.x*bml; acc[9]+=a2.y*bml; acc[10]+=a2.z*bml; acc[11]+=a2.w*bml;
    acc[12]+=a3.x*bml; acc[13]+=a3.y*bml; acc[14]+=a3.z*bml; acc[15]+=a3.w*bml;
    gsa += bml;
  }
  float* gp = Gpart + ((size_t)(b*16+ch))*4096 + wid*16*64;
  #pragma unroll
  for(int q=0;q<16;q++) gp[q*64+lane]=acc[q];
  if(wid==0) gspart[(b*16+ch)*64+lane]=gsa;
}

// ---------------- partial column sums of weight/weightf ----------------
__global__ __launch_bounds__(256) void k_wsum_part(const float* __restrict__ weight,
                                                   const float* __restrict__ weightf,
                                                   float* __restrict__ wsp,
                                                   float* __restrict__ wfsp)
{
  int jjblk = blockIdx.x&3, ns = blockIdx.x>>2;   // grid 32
  int jj = jjblk*256 + threadIdx.x;
  float s=0.f, sf=0.f;
  for(int n=ns*128; n<ns*128+128; n++){ s += weight[n*1024+jj]; sf += weightf[n*1024+jj]; }
  wsp [ns*1024+jj]=s;
  wfsp[ns*1024+jj]=sf;
}

// ---------------- Ppart = partial of weight^T@Vinu + weightf^T@Vinf ----------------
__global__ __launch_bounds__(256) void k_pw(const float* __restrict__ weight,
                                            const float* __restrict__ weightf,
                                            const float* __restrict__ Vin,
                                            float* __restrict__ Ppart)
{
  int bid = blockIdx.x;                           // 8b x 16jjt x 4ns = 512
  int ns = bid&3, jjt = (bid>>2)&15, b = bid>>6;
  int lane = threadIdx.x&63;
  int wid = __builtin_amdgcn_readfirstlane(threadIdx.x>>6);
  int jj0 = jjt*64 + wid*16;
  const float* Vu = Vin + (size_t)b*NTOK2*FD;
  const float* Vf = Vu + NTOKEN*FD;
  float acc[16];
  #pragma unroll
  for(int q=0;q<16;q++) acc[q]=0.f;
  for(int n=ns*256; n<ns*256+256; n++){
    float vu = Vu[n*64+lane];
    float vf = Vf[n*64+lane];
    const float* wr  = weight  + n*1024 + jj0;    // wave-uniform -> scalar loads
    const float* wfr = weightf + n*1024 + jj0;
    #pragma unroll
    for(int q=0;q<16;q++) acc[q] += wr[q]*vu + wfr[q]*vf;
  }
  float* pp = Ppart + ((size_t)(b*4+ns)*1024 + jjt*64 + wid*16)*64;
  #pragma unroll
  for(int q=0;q<16;q++) pp[q*64+lane]=acc[q];
}

// ---------------- result = dxdy^2*(P@T3 + (wsum+wfsum)⊗t3)  (scale in T3/t3) -------
__global__ __launch_bounds__(256) void k_final(const float* __restrict__ Ppart,
                                               const float* __restrict__ T3,
                                               const float* __restrict__ t3,
                                               const float* __restrict__ wsp,
                                               const float* __restrict__ wfsp,
                                               float* __restrict__ out)
{
  int wid = __builtin_amdgcn_readfirstlane(threadIdx.x>>6);
  int row = blockIdx.x*4 + wid;                   // b*1024+jj, total 8192
  int lane = threadIdx.x&63;
  int b = row>>10, jj = row&1023;
  float p = 0.f;
  #pragma unroll
  for(int ns=0; ns<4; ns++) p += Ppart[((size_t)(b*4+ns)*1024 + jj)*64 + lane];
  float wsm = 0.f;
  #pragma unroll
  for(int ns=0; ns<8; ns++) wsm += wsp[ns*1024+jj] + wfsp[ns*1024+jj];
  const float* Tb = T3 + b*4096;
  float acc = wsm * t3[b*64+lane];
  #pragma unroll
  for(int c=0;c<64;c++) acc += __shfl(p, c) * Tb[c*64+lane];
  out[(size_t)row*64+lane] = acc * (DXDY*DXDY);
}

extern "C" void kernel_launch(void* const* d_in, const int* in_sizes, int n_in,
                              void* d_out, int out_size, void* d_ws, size_t ws_size,
                              hipStream_t stream)
{
  (void)in_sizes; (void)n_in; (void)out_size; (void)ws_size;
  const float* xy   = (const float*)d_in[0];
  const float* kW0  = (const float*)d_in[1];
  const float* kb0  = (const float*)d_in[2];
  const float* kW1  = (const float*)d_in[3];
  const float* kb1  = (const float*)d_in[4];
  const float* kW2  = (const float*)d_in[5];
  const float* kb2  = (const float*)d_in[6];
  const float* fW0  = (const float*)d_in[7];
  const float* fb0  = (const float*)d_in[8];
  const float* fW1  = (const float*)d_in[9];
  const float* fb1  = (const float*)d_in[10];
  const float* fW2  = (const float*)d_in[11];
  const float* fb2  = (const float*)d_in[12];
  const float* Wq   = (const float*)d_in[13];
  const float* bq   = (const float*)d_in[14];
  const float* Wk   = (const float*)d_in[15];
  const float* bk   = (const float*)d_in[16];
  const float* ln0g = (const float*)d_in[17];
  const float* ln0b = (const float*)d_in[18];
  const float* lng  = (const float*)d_in[19];
  const float* lnb  = (const float*)d_in[20];
  float* out = (float*)d_out;
  float* ws  = (float*)d_ws;

  float* Vin    = ws + OFF_VIN;
  float* weight = ws + OFF_W;
  float* weightf= ws + OFF_WF;
  float* Gpart  = ws + OFF_GPART;
  float* gspart = ws + OFF_GSPART;
  float* Mm     = ws + OFF_M;
  float* uu     = ws + OFF_U;
  float* vv     = ws + OFF_V;
  float* cc     = ws + OFF_C;
  float* lnp    = ws + OFF_LNP;
  float* T      = ws + OFF_T;
  float* tvv    = ws + OFF_TV;
  float* T3     = ws + OFF_T3;
  float* t3     = ws + OFF_T3V;
  float* wsp    = ws + OFF_WSP;
  float* wfsp   = ws + OFF_WFSP;
  float* Ppart  = ws + OFF_PPART;

  k_tables<<<1024, 32, 0, stream>>>(kW0, kb0, fW0, fb0, ws);
  k_mlp<<<8192, 256, 0, stream>>>(kW1, kb1, kW2, kb2, fW1, fb1, fW2, fb2,
                                  ws, weight, weightf);
  k_ln0_part<<<128, 256, 0, stream>>>(xy, lnp);
  k_prep<<<4, 256, 0, stream>>>(Wq, bq, Wk, bk, Mm, uu, vv, cc);
  k_ln0ag<<<256, 256, 0, stream>>>(xy, ln0g, ln0b, lnp, Vin, Gpart, gspart);

  for(int j=0;j<3;j++){
    k_redT<<<BATCH, 256, 0, stream>>>(Gpart, gspart, 32, Mm, uu, vv, cc, j, T, tvv);
    k_mid_gram<<<256, 256, 0, stream>>>(Vin, T, tvv, lng, lnb, j, (j<2)?1:0,
                                        Gpart, gspart);
  }

  k_gram_fin<<<128, 256, 0, stream>>>(Vin, xy, Gpart, gspart);
  k_redT<<<BATCH, 256, 0, stream>>>(Gpart, gspart, 16, Mm, uu, vv, cc, 3, T3, t3);

  k_wsum_part<<<32, 256, 0, stream>>>(weight, weightf, wsp, wfsp);
  k_pw<<<512, 256, 0, stream>>>(weight, weightf, Vin, Ppart);
  k_final<<<BATCH*1024/4, 256, 0, stream>>>(Ppart, T3, t3, wsp, wfsp, out);
}